// Round 2
// baseline (281.763 us; speedup 1.0000x reference)
//
#include <hip/hip_runtime.h>
#include <hip/hip_bf16.h>

// Inputs fp32, outputs fp32. Internal bf16 MFMA pipeline.
// R7: de-staging. attn kernel: K/V fragments loaded DIRECTLY global->VGPR
// (L2-resident operands), zero barriers, LDS only for the wave-private P
// transpose. qkv kernel: B (Wt) fragments direct from L2; A (x) stays
// async-staged but double-buffered with ONE barrier per K-step and the
// prefetch issued before compute (T3-minimal). Normalization still deferred
// to finalize (R6 structure).

typedef __attribute__((ext_vector_type(8))) short bf16x8;
typedef __attribute__((ext_vector_type(4))) float f32x4;

#define NB 8
#define NT 2048
#define NC 1024
#define NH 64

__device__ __forceinline__ unsigned short f2bf(float f) {
    unsigned int u = __builtin_bit_cast(unsigned int, f);
    u += 0x7fffu + ((u >> 16) & 1u);   // RNE
    return (unsigned short)(u >> 16);
}

__device__ __forceinline__ bf16x8 cvt8(float4 a, float4 b) {
    union { bf16x8 v; __hip_bfloat162 h[4]; } u;
    u.h[0] = __float22bfloat162_rn(make_float2(a.x, a.y));
    u.h[1] = __float22bfloat162_rn(make_float2(a.z, a.w));
    u.h[2] = __float22bfloat162_rn(make_float2(b.x, b.y));
    u.h[3] = __float22bfloat162_rn(make_float2(b.z, b.w));
    return u.v;
}

// async 16B global->LDS; lds ptr must be wave-uniform (HW adds lane*16).
__device__ __forceinline__ void async_ld16(const void* g, const void* l) {
    __builtin_amdgcn_global_load_lds(
        (const __attribute__((address_space(1))) unsigned int*)g,
        (__attribute__((address_space(3))) unsigned int*)(unsigned int)(unsigned long long)l,
        16, 0, 0);
}

// ---------------------------------------------------------------------------
// Kernel 0: W fp32 [1024][64] -> Wt bf16 [3][64][1024] (transposed), 1/32
// score scale folded into Wq (power of two, lossless).
// ---------------------------------------------------------------------------
__global__ __launch_bounds__(256) void wt_kernel(
        const float* __restrict__ Wq,
        const float* __restrict__ Wk,
        const float* __restrict__ Wv,
        unsigned short* __restrict__ Wt) {
    __shared__ float tile[64][65];
    int m  = blockIdx.x >> 4;
    int k0 = (blockIdx.x & 15) * 64;
    const float* W = (m == 0) ? Wq : ((m == 1) ? Wk : Wv);
    int tid = threadIdx.x;
    for (int i = 0; i < 4; ++i) {
        int f = tid + i * 256;
        int r = f >> 4, c4 = (f & 15) * 4;
        float4 v = *(const float4*)&W[(size_t)(k0 + r) * 64 + c4];
        tile[r][c4 + 0] = v.x; tile[r][c4 + 1] = v.y;
        tile[r][c4 + 2] = v.z; tile[r][c4 + 3] = v.w;
    }
    __syncthreads();
    int n  = tid & 63;
    int kq = (tid >> 6) * 16;
    float scale = (m == 0) ? 0.03125f : 1.0f;
    __attribute__((aligned(16))) unsigned short outv[16];
    for (int j = 0; j < 16; ++j)
        outv[j] = f2bf(tile[kq + j][n] * scale);
    unsigned short* dst = &Wt[(size_t)m * (64 * 1024) + (size_t)n * 1024 + k0 + kq];
    *(uint4*)dst       = *(const uint4*)&outv[0];
    *(uint4*)(dst + 8) = *(const uint4*)&outv[8];
}

// ---------------------------------------------------------------------------
// Kernel 1: qkv GEMM. Grid 512: 32 rows/block, N=192 (q|k|v).
// A (x fp32 32x64) double-buffered via global_load_lds (XOR swizzle), ONE
// barrier per K-step, prefetch of kb+1 issued before compute. B (Wt bf16,
// 384 KB, L2-resident) fragments loaded directly global->VGPR each step.
// q,k stored row-major bf16; v stored TRANSPOSED [b][h][t] for attn.
// ---------------------------------------------------------------------------
__global__ __launch_bounds__(256) void qkv_kernel(
        const float* __restrict__ x,
        const unsigned short* __restrict__ Wt,
        unsigned short* __restrict__ qkv,
        unsigned short* __restrict__ v_t) {
    __shared__ float At[2 * 32 * 64];         // 2 x 8 KB, swizzled chunks
    char* Ab = (char*)At;

    int tid  = threadIdx.x;
    int wave = tid >> 6, lane = tid & 63, quad = lane >> 4, l15 = lane & 15;
    int row0 = blockIdx.x * 32;

    f32x4 acc[2][3];
#pragma unroll
    for (int rt = 0; rt < 2; ++rt)
#pragma unroll
        for (int j = 0; j < 3; ++j) acc[rt][j] = (f32x4){0.f, 0.f, 0.f, 0.f};

    // prologue: stage kb=0 into buffer 0
#pragma unroll
    for (int i = 0; i < 2; ++i) {
        int s = i * 256 + tid;
        int m = s >> 4, p = s & 15;
        int j = (p & 8) | ((p & 7) ^ (m & 7));
        async_ld16(x + (size_t)(row0 + m) * NC + j * 4,
                   Ab + i * 4096 + wave * 1024);
    }
    __syncthreads();                           // buf0 ready

    int cur = 0;
    for (int kb = 0; kb < 16; ++kb) {
        if (kb < 15) {                         // prefetch kb+1 -> other buffer
#pragma unroll
            for (int i = 0; i < 2; ++i) {
                int s = i * 256 + tid;
                int m = s >> 4, p = s & 15;
                int j = (p & 8) | ((p & 7) ^ (m & 7));
                async_ld16(x + (size_t)(row0 + m) * NC + (kb + 1) * 64 + j * 4,
                           Ab + (cur ^ 1) * 8192 + i * 4096 + wave * 1024);
            }
        }
        // B fragments direct from L2 (each wave owns 3 distinct n-tiles)
        bf16x8 bfr[2][3];
#pragma unroll
        for (int jj = 0; jj < 3; ++jj) {
            int n = (wave * 3 + jj) * 16 + l15;
            const unsigned short* bp = Wt + (size_t)n * NC + kb * 64 + quad * 8;
            bfr[0][jj] = *(const bf16x8*)bp;
            bfr[1][jj] = *(const bf16x8*)(bp + 32);
        }
#pragma unroll
        for (int c = 0; c < 2; ++c) {
            bf16x8 af[2];
#pragma unroll
            for (int rt = 0; rt < 2; ++rt) {
                int m  = rt * 16 + l15;
                int j0 = c * 8 + quad * 2;
                int p0 = (j0 & 8) | ((j0 & 7) ^ (m & 7));
                int p1 = (j0 & 8) | (((j0 + 1) & 7) ^ (m & 7));
                float4 a0 = *(const float4*)(Ab + cur * 8192 + m * 256 + p0 * 16);
                float4 a1 = *(const float4*)(Ab + cur * 8192 + m * 256 + p1 * 16);
                af[rt] = cvt8(a0, a1);
            }
#pragma unroll
            for (int jj = 0; jj < 3; ++jj)
#pragma unroll
                for (int rt = 0; rt < 2; ++rt)
                    acc[rt][jj] = __builtin_amdgcn_mfma_f32_16x16x32_bf16(
                        af[rt], bfr[c][jj], acc[rt][jj], 0, 0, 0);
        }
        __syncthreads();   // drains prefetch vmcnt + all ds reads of cur buf
        cur ^= 1;
    }

    int b = row0 >> 11;
#pragma unroll
    for (int jj = 0; jj < 3; ++jj) {
        int g   = wave * 3 + jj;
        int mat = g >> 2;
        int col = (g & 3) * 16 + l15;
#pragma unroll
        for (int rt = 0; rt < 2; ++rt) {
            int rowb = row0 + rt * 16 + quad * 4;
            if (mat < 2) {
#pragma unroll
                for (int r = 0; r < 4; ++r)
                    qkv[(size_t)mat * (16384 * 64) + (size_t)(rowb + r) * 64 + col] =
                        f2bf(acc[rt][jj][r]);
            } else {
                union { unsigned long long q; unsigned short us[4]; } pk;
#pragma unroll
                for (int r = 0; r < 4; ++r) pk.us[r] = f2bf(acc[rt][jj][r]);
                *(unsigned long long*)&v_t[((size_t)b * 64 + col) * NT + (rowb & 2047)] = pk.q;
            }
        }
    }
}

// ---------------------------------------------------------------------------
// Kernel 2: single score pass, barrier-free. Grid (128, 8): bx = it*4 + qq.
// K/V fragments loaded directly global->VGPR (both L2-resident); LDS holds
// only the wave-private P transpose buffer. Writes UNNORMALIZED e to attn,
// rowsums -> atomic l, unnormalized PV -> atomic res.
// ---------------------------------------------------------------------------
__global__ __launch_bounds__(256) void attn_u_kernel(
        const unsigned short* __restrict__ qg,
        const unsigned short* __restrict__ kg,
        const unsigned short* __restrict__ vtg,
        float* __restrict__ l,
        float* __restrict__ res,
        float* __restrict__ attn) {
    __shared__ float ptf[4 * 16 * 68];        // per-wave e [row][s], pad 4

    int tid  = threadIdx.x;
    int wave = tid >> 6, lane = tid & 63, quad = lane >> 4, l15 = lane & 15;
    int it = blockIdx.x >> 2, qq = blockIdx.x & 3;
    int b  = blockIdx.y;
    if (qq > it) return;
    int t0 = it * 64;
    size_t brow = (size_t)b * NT;

    bf16x8 qf[2];
    {
        const unsigned short* qp = qg + (brow + t0 + wave * 16 + l15) * NH + quad * 8;
        qf[0] = *(const bf16x8*)qp;
        qf[1] = *(const bf16x8*)(qp + 32);
    }
    int trow[4];
#pragma unroll
    for (int r = 0; r < 4; ++r) trow[r] = t0 + wave * 16 + quad * 4 + r;

    f32x4 oacc[4];
#pragma unroll
    for (int nt = 0; nt < 4; ++nt) oacc[nt] = (f32x4){0.f, 0.f, 0.f, 0.f};
    float rs[4] = {0.f, 0.f, 0.f, 0.f};

    for (int st = qq; st <= it; st += 4) {
        // K fragments: 8 independent 16B loads, issue all then consume
        bf16x8 kf[2][4];
#pragma unroll
        for (int nt = 0; nt < 4; ++nt) {
            const unsigned short* kp =
                kg + (brow + st * 64 + nt * 16 + l15) * NH + quad * 8;
            kf[0][nt] = *(const bf16x8*)kp;
            kf[1][nt] = *(const bf16x8*)(kp + 32);
        }

        f32x4 sacc[4];
#pragma unroll
        for (int nt = 0; nt < 4; ++nt) sacc[nt] = (f32x4){0.f, 0.f, 0.f, 0.f};
#pragma unroll
        for (int c = 0; c < 2; ++c)
#pragma unroll
            for (int nt = 0; nt < 4; ++nt)
                sacc[nt] = __builtin_amdgcn_mfma_f32_16x16x32_bf16(
                    qf[c], kf[c][nt], sacc[nt], 0, 0, 0);

        // V fragments issued now; latency hides under exp/ptf/stores
        bf16x8 vf[2][4];
#pragma unroll
        for (int nt = 0; nt < 4; ++nt) {
            const unsigned short* vp =
                vtg + ((size_t)b * 64 + nt * 16 + l15) * NT + st * 64 + quad * 8;
            vf[0][nt] = *(const bf16x8*)vp;
            vf[1][nt] = *(const bf16x8*)(vp + 32);
        }

        bool dia = (st == it);
#pragma unroll
        for (int nt = 0; nt < 4; ++nt) {
            int s_g = st * 64 + nt * 16 + l15;
#pragma unroll
            for (int r = 0; r < 4; ++r) {
                float e = __expf(sacc[nt][r]);
                if (dia && s_g > trow[r]) e = 0.f;
                rs[r] += e;
                ptf[wave * 1088 + (quad * 4 + r) * 68 + nt * 16 + l15] = e;
            }
        }
        asm volatile("s_waitcnt lgkmcnt(0)" ::: "memory");  // wave-internal RAW

        // coalesced attn stores (unnormalized): 16 lanes x 16 B per row
#pragma unroll
        for (int r = 0; r < 4; ++r) {
            int row = quad * 4 + r;
            float4 pv = *(const float4*)&ptf[wave * 1088 + row * 68 + l15 * 4];
            *(float4*)&attn[(brow + t0 + wave * 16 + row) * NT + st * 64 + l15 * 4] = pv;
        }

        // PV (unnormalized): A-frag from ptf (row l15, k = c*32+quad*8)
#pragma unroll
        for (int c = 0; c < 2; ++c) {
            const float* pp = &ptf[wave * 1088 + l15 * 68 + c * 32 + quad * 8];
            float4 a0 = *(const float4*)pp;
            float4 a1 = *(const float4*)(pp + 4);
            bf16x8 pf = cvt8(a0, a1);
#pragma unroll
            for (int nt = 0; nt < 4; ++nt)
                oacc[nt] = __builtin_amdgcn_mfma_f32_16x16x32_bf16(
                    pf, vf[c][nt], oacc[nt], 0, 0, 0);
        }
    }

    // rowsum partials -> l
#pragma unroll
    for (int r = 0; r < 4; ++r) {
        float v = rs[r];
        v += __shfl_xor(v, 1, 16);
        v += __shfl_xor(v, 2, 16);
        v += __shfl_xor(v, 4, 16);
        v += __shfl_xor(v, 8, 16);
        if (l15 == 0)
            unsafeAtomicAdd(&l[brow + trow[r]], v);
    }

#pragma unroll
    for (int nt = 0; nt < 4; ++nt)
#pragma unroll
        for (int r = 0; r < 4; ++r)
            unsafeAtomicAdd(&res[(brow + trow[r]) * NH + nt * 16 + l15], oacc[nt][r]);
}

// ---------------------------------------------------------------------------
// Kernel 3: finalize. Grid (1024, 8): it = bx>>5, st = bx&31.
// st > it: write zeros. st <= it: scale attn tile rows by 1/l[row].
// st == it: additionally scale the res rows for this row-tile.
// ---------------------------------------------------------------------------
__global__ __launch_bounds__(256) void finalize_kernel(
        const float* __restrict__ l,
        float* __restrict__ res,
        float* __restrict__ attn) {
    __shared__ float rinv[64];
    int bx = blockIdx.x;
    int it = bx >> 5, st = bx & 31;
    int b  = blockIdx.y;
    size_t brow = (size_t)b * NT;
    int t0 = it * 64;
    int tid = threadIdx.x;

    if (st > it) {
        float4 z4 = {0.f, 0.f, 0.f, 0.f};
#pragma unroll
        for (int k = 0; k < 4; ++k) {
            int f = tid + k * 256;
            int r = f >> 4, c4 = (f & 15) * 4;
            *(float4*)&attn[(brow + t0 + r) * NT + st * 64 + c4] = z4;
        }
        return;
    }

    if (tid < 64) rinv[tid] = 1.0f / l[brow + t0 + tid];
    __syncthreads();

#pragma unroll
    for (int k = 0; k < 4; ++k) {
        int f = tid + k * 256;
        int r = f >> 4, c4 = (f & 15) * 4;
        float* p = &attn[(brow + t0 + r) * NT + st * 64 + c4];
        float4 v = *(const float4*)p;
        float s = rinv[r];
        v.x *= s; v.y *= s; v.z *= s; v.w *= s;
        *(float4*)p = v;
    }

    if (st == it) {   // diagonal block also scales res rows t0..t0+63
#pragma unroll
        for (int k = 0; k < 4; ++k) {
            int f = tid + k * 256;
            int r = f >> 4, c4 = (f & 15) * 4;
            float* p = &res[(brow + t0 + r) * NH + c4];
            float4 v = *(const float4*)p;
            float s = rinv[r];
            v.x *= s; v.y *= s; v.z *= s; v.w *= s;
            *(float4*)p = v;
        }
    }
}

// ---------------------------------------------------------------------------
extern "C" void kernel_launch(void* const* d_in, const int* in_sizes, int n_in,
                              void* d_out, int out_size, void* d_ws, size_t ws_size,
                              hipStream_t stream) {
    const float* x  = (const float*)d_in[0];
    const float* Wq = (const float*)d_in[1];
    const float* Wk = (const float*)d_in[2];
    const float* Wv = (const float*)d_in[3];

    unsigned short* ws  = (unsigned short*)d_ws;
    unsigned short* Wt  = ws;                          // 3*64*1024 bf16
    unsigned short* qkv = ws + 3 * 64 * 1024;          // 2*16384*64 bf16 (q,k)
    unsigned short* v_t = qkv + 2 * 16384 * 64;        // 16384*64 bf16 [b][h][t]
    float* l = (float*)(v_t + 16384 * 64);             // 16384 fp32

    float* res  = (float*)d_out;                       // [8,2048,64]
    float* attn = res + (size_t)NB * NT * NH;          // [8,2048,2048]

    hipMemsetAsync(l, 0, (size_t)NB * NT * sizeof(float), stream);
    hipMemsetAsync(res, 0, (size_t)NB * NT * NH * sizeof(float), stream);

    hipLaunchKernelGGL(wt_kernel, dim3(48), dim3(256), 0, stream, Wq, Wk, Wv, Wt);
    hipLaunchKernelGGL(qkv_kernel, dim3(512), dim3(256), 0, stream, x, Wt, qkv, v_t);

    const unsigned short* qg = qkv;
    const unsigned short* kg = qkv + 16384 * 64;

    hipLaunchKernelGGL(attn_u_kernel, dim3(128, 8), dim3(256), 0, stream,
                       qg, kg, v_t, l, res, attn);
    hipLaunchKernelGGL(finalize_kernel, dim3(1024, 8), dim3(256), 0, stream,
                       l, res, attn);
}

// Round 5
// 230.150 us; speedup vs baseline: 1.2243x; 1.2243x over previous
//
#include <hip/hip_runtime.h>
#include <hip/hip_bf16.h>

// Inputs fp32, outputs fp32. Internal bf16 MFMA pipeline.
// R9/R11: R8's double-buffered one-barrier pipeline + EXPLICIT vmcnt(0)
// drain before each loop-top __syncthreads. R8's NaN: the prefetch
// global_load_lds sits in a different basic block (if-guard) and is consumed
// across the loop back-edge; LLVM's LDS-DMA alias tracking loses it and
// emits no vmcnt wait, so first-iteration ds_reads raced the DMA. The
// explicit wait restores the drain unconditionally (it is what the compiler
// emits in the straight-line R5 shape) at zero cost -- the DMA had the whole
// compute phase to land. (R10 = this, minus one stray paren.)

typedef __attribute__((ext_vector_type(8))) short bf16x8;
typedef __attribute__((ext_vector_type(4))) float f32x4;

#define NB 8
#define NT 2048
#define NC 1024
#define NH 64

#define VM_DRAIN() asm volatile("s_waitcnt vmcnt(0)" ::: "memory")

__device__ __forceinline__ unsigned short f2bf(float f) {
    unsigned int u = __builtin_bit_cast(unsigned int, f);
    u += 0x7fffu + ((u >> 16) & 1u);   // RNE
    return (unsigned short)(u >> 16);
}

__device__ __forceinline__ bf16x8 cvt8(float4 a, float4 b) {
    union { bf16x8 v; __hip_bfloat162 h[4]; } u;
    u.h[0] = __float22bfloat162_rn(make_float2(a.x, a.y));
    u.h[1] = __float22bfloat162_rn(make_float2(a.z, a.w));
    u.h[2] = __float22bfloat162_rn(make_float2(b.x, b.y));
    u.h[3] = __float22bfloat162_rn(make_float2(b.z, b.w));
    return u.v;
}

// async 16B global->LDS; lds ptr must be wave-uniform (HW adds lane*16).
__device__ __forceinline__ void async_ld16(const void* g, const void* l) {
    __builtin_amdgcn_global_load_lds(
        (const __attribute__((address_space(1))) unsigned int*)g,
        (__attribute__((address_space(3))) unsigned int*)(unsigned int)(unsigned long long)l,
        16, 0, 0);
}

// ---------------------------------------------------------------------------
// Kernel 0: W fp32 [1024][64] -> Wt bf16 [3][64][1024] (transposed), 1/32
// score scale folded into Wq (power of two, lossless).
// ---------------------------------------------------------------------------
__global__ __launch_bounds__(256) void wt_kernel(
        const float* __restrict__ Wq,
        const float* __restrict__ Wk,
        const float* __restrict__ Wv,
        unsigned short* __restrict__ Wt) {
    __shared__ float tile[64][65];
    int m  = blockIdx.x >> 4;
    int k0 = (blockIdx.x & 15) * 64;
    const float* W = (m == 0) ? Wq : ((m == 1) ? Wk : Wv);
    int tid = threadIdx.x;
    for (int i = 0; i < 4; ++i) {
        int f = tid + i * 256;
        int r = f >> 4, c4 = (f & 15) * 4;
        float4 v = *(const float4*)&W[(size_t)(k0 + r) * 64 + c4];
        tile[r][c4 + 0] = v.x; tile[r][c4 + 1] = v.y;
        tile[r][c4 + 2] = v.z; tile[r][c4 + 3] = v.w;
    }
    __syncthreads();
    int n  = tid & 63;
    int kq = (tid >> 6) * 16;
    float scale = (m == 0) ? 0.03125f : 1.0f;
    __attribute__((aligned(16))) unsigned short outv[16];
    for (int j = 0; j < 16; ++j)
        outv[j] = f2bf(tile[kq + j][n] * scale);
    unsigned short* dst = &Wt[(size_t)m * (64 * 1024) + (size_t)n * 1024 + k0 + kq];
    *(uint4*)dst       = *(const uint4*)&outv[0];
    *(uint4*)(dst + 8) = *(const uint4*)&outv[8];
}

// ---------------------------------------------------------------------------
// Kernel 1: qkv GEMM. Grid 512: 32 rows/block, N=192 (q|k|v).
// A (x fp32 32x64) + B (Wt bf16 192x64) double-buffered via global_load_lds
// (XOR swizzle); ONE barrier per K-step, prefetch kb+1 issued pre-compute,
// explicit vmcnt(0) drain before the barrier. 64 KB LDS = 2 blocks/CU.
// ---------------------------------------------------------------------------
__global__ __launch_bounds__(256) void qkv_kernel(
        const float* __restrict__ x,
        const unsigned short* __restrict__ Wt,
        unsigned short* __restrict__ qkv,
        unsigned short* __restrict__ v_t) {
    __shared__ char smem[65536];

    int tid  = threadIdx.x;
    int wave = tid >> 6, lane = tid & 63, quad = lane >> 4, l15 = lane & 15;
    int row0 = blockIdx.x * 32;

    f32x4 acc[2][3];
#pragma unroll
    for (int rt = 0; rt < 2; ++rt)
#pragma unroll
        for (int j = 0; j < 3; ++j) acc[rt][j] = (f32x4){0.f, 0.f, 0.f, 0.f};

    // prologue: stage kb=0 into buf0
#pragma unroll
    for (int i = 0; i < 2; ++i) {              // A: 32 rows x 256 B
        int s = i * 256 + tid;
        int m = s >> 4, p = s & 15;
        int j = (p & 8) | ((p & 7) ^ (m & 7));
        async_ld16(x + (size_t)(row0 + m) * NC + j * 4,
                   smem + i * 4096 + wave * 1024);
    }
#pragma unroll
    for (int i = 0; i < 6; ++i) {              // B: 192 rows x 128 B
        int s = i * 256 + tid;
        int n = s >> 3, p = s & 7;
        int j = p ^ (n & 7);
        async_ld16(Wt + (size_t)n * NC + j * 8,
                   smem + 8192 + i * 4096 + wave * 1024);
    }

    int cur = 0;
    for (int kb = 0; kb < 16; ++kb) {
        VM_DRAIN();                            // prev prefetch landed in LDS
        __syncthreads();                       // buf[cur] ready for all waves
        if (kb < 15) {                         // prefetch kb+1 -> buf[cur^1]
            char* nb = smem + (cur ^ 1) * 32768;
#pragma unroll
            for (int i = 0; i < 2; ++i) {
                int s = i * 256 + tid;
                int m = s >> 4, p = s & 15;
                int j = (p & 8) | ((p & 7) ^ (m & 7));
                async_ld16(x + (size_t)(row0 + m) * NC + (kb + 1) * 64 + j * 4,
                           nb + i * 4096 + wave * 1024);
            }
#pragma unroll
            for (int i = 0; i < 6; ++i) {
                int s = i * 256 + tid;
                int n = s >> 3, p = s & 7;
                int j = p ^ (n & 7);
                async_ld16(Wt + (size_t)n * NC + (kb + 1) * 64 + j * 8,
                           nb + 8192 + i * 4096 + wave * 1024);
            }
        }
        char* Ab = smem + cur * 32768;
        char* Bb = Ab + 8192;
#pragma unroll
        for (int c = 0; c < 2; ++c) {
            bf16x8 af[2];
#pragma unroll
            for (int rt = 0; rt < 2; ++rt) {
                int m  = rt * 16 + l15;
                int j0 = c * 8 + quad * 2;
                int p0 = (j0 & 8) | ((j0 & 7) ^ (m & 7));
                int p1 = (j0 & 8) | (((j0 + 1) & 7) ^ (m & 7));
                float4 a0 = *(const float4*)(Ab + m * 256 + p0 * 16);
                float4 a1 = *(const float4*)(Ab + m * 256 + p1 * 16);
                af[rt] = cvt8(a0, a1);
            }
#pragma unroll
            for (int jj = 0; jj < 3; ++jj) {
                int n = (wave * 3 + jj) * 16 + l15;
                int p = (c * 4 + quad) ^ (n & 7);
                bf16x8 bf = *(const bf16x8*)(Bb + n * 128 + p * 16);
#pragma unroll
                for (int rt = 0; rt < 2; ++rt)
                    acc[rt][jj] = __builtin_amdgcn_mfma_f32_16x16x32_bf16(
                        af[rt], bf, acc[rt][jj], 0, 0, 0);
            }
        }
        cur ^= 1;
    }

    int b = row0 >> 11;
#pragma unroll
    for (int jj = 0; jj < 3; ++jj) {
        int g   = wave * 3 + jj;
        int mat = g >> 2;
        int col = (g & 3) * 16 + l15;
#pragma unroll
        for (int rt = 0; rt < 2; ++rt) {
            int rowb = row0 + rt * 16 + quad * 4;
            if (mat < 2) {
#pragma unroll
                for (int r = 0; r < 4; ++r)
                    qkv[(size_t)mat * (16384 * 64) + (size_t)(rowb + r) * 64 + col] =
                        f2bf(acc[rt][jj][r]);
            } else {
                union { unsigned long long q; unsigned short us[4]; } pk;
#pragma unroll
                for (int r = 0; r < 4; ++r) pk.us[r] = f2bf(acc[rt][jj][r]);
                *(unsigned long long*)&v_t[((size_t)b * 64 + col) * NT + (rowb & 2047)] = pk.q;
            }
        }
    }
}

// ---------------------------------------------------------------------------
// Kernel 2: rowsums. Grid (128, 8): bx = it*4 + qq; tiles st = qq, qq+4, ...
// K tile double-buffered, one barrier per tile (explicit vmcnt drain),
// prefetch before compute.
// ---------------------------------------------------------------------------
__global__ __launch_bounds__(256) void lsum_kernel(
        const unsigned short* __restrict__ qg,
        const unsigned short* __restrict__ kg,
        float* __restrict__ l) {
    __shared__ unsigned short kt[2 * 64 * 64];
    char* ktb = (char*)kt;
    int tid  = threadIdx.x;
    int wave = tid >> 6, lane = tid & 63, quad = lane >> 4, l15 = lane & 15;
    int it = blockIdx.x >> 2, qq = blockIdx.x & 3;
    int b  = blockIdx.y;
    if (qq > it) return;
    int t0 = it * 64;
    size_t brow = (size_t)b * NT;

    bf16x8 qf[2];
    {
        const unsigned short* qp = qg + (brow + t0 + wave * 16 + l15) * NH + quad * 8;
        qf[0] = *(const bf16x8*)qp;
        qf[1] = *(const bf16x8*)(qp + 32);
    }
    int trow[4];
#pragma unroll
    for (int r = 0; r < 4; ++r) trow[r] = t0 + wave * 16 + quad * 4 + r;

    // prologue: stage st=qq into buf0
#pragma unroll
    for (int i = 0; i < 2; ++i) {
        int s = i * 256 + tid;
        int r = s >> 3, p = s & 7;
        int j = p ^ (r & 7);
        async_ld16(kg + (brow + qq * 64 + r) * NH + j * 8,
                   ktb + i * 4096 + wave * 1024);
    }

    float rs[4] = {0.f, 0.f, 0.f, 0.f};
    int cur = 0;

    for (int st = qq; st <= it; st += 4) {
        VM_DRAIN();                            // prev prefetch landed in LDS
        __syncthreads();                       // buf[cur] ready for all waves
        if (st + 4 <= it) {                    // prefetch next K tile
#pragma unroll
            for (int i = 0; i < 2; ++i) {
                int s = i * 256 + tid;
                int r = s >> 3, p = s & 7;
                int j = p ^ (r & 7);
                async_ld16(kg + (brow + (st + 4) * 64 + r) * NH + j * 8,
                           ktb + (cur ^ 1) * 8192 + i * 4096 + wave * 1024);
            }
        }
        char* kb = ktb + cur * 8192;

        f32x4 sacc[4];
#pragma unroll
        for (int nt = 0; nt < 4; ++nt) sacc[nt] = (f32x4){0.f, 0.f, 0.f, 0.f};
#pragma unroll
        for (int c = 0; c < 2; ++c)
#pragma unroll
            for (int nt = 0; nt < 4; ++nt) {
                int n = nt * 16 + l15;
                int p = (c * 4 + quad) ^ (n & 7);
                bf16x8 kf = *(const bf16x8*)(kb + n * 128 + p * 16);
                sacc[nt] = __builtin_amdgcn_mfma_f32_16x16x32_bf16(qf[c], kf, sacc[nt], 0, 0, 0);
            }
        bool dia = (st == it);
#pragma unroll
        for (int nt = 0; nt < 4; ++nt) {
            int s_g = st * 64 + nt * 16 + l15;
#pragma unroll
            for (int r = 0; r < 4; ++r) {
                float e = __expf(sacc[nt][r]);
                if (dia && s_g > trow[r]) e = 0.f;
                rs[r] += e;
            }
        }
        cur ^= 1;
    }
#pragma unroll
    for (int r = 0; r < 4; ++r) {
        float v = rs[r];
        v += __shfl_xor(v, 1, 16);
        v += __shfl_xor(v, 2, 16);
        v += __shfl_xor(v, 4, 16);
        v += __shfl_xor(v, 8, 16);
        if (l15 == 0)
            unsafeAtomicAdd(&l[brow + trow[r]], v);
    }
}

// ---------------------------------------------------------------------------
// Kernel 3: attn write + PV. Grid (128, 8): bx = it*4 + qq, tiles strided 4.
// K and V^T double-buffered, one barrier per tile (explicit vmcnt drain),
// prefetch before compute. P staged fp32 in LDS -> coalesced 16B attn
// stores + PV A-frags; partial O atomic-added into zeroed res.
// ---------------------------------------------------------------------------
__global__ __launch_bounds__(256) void attn_m_kernel(
        const unsigned short* __restrict__ qg,
        const unsigned short* __restrict__ kg,
        const unsigned short* __restrict__ vtg,
        const float* __restrict__ l,
        float* __restrict__ res,
        float* __restrict__ attn) {
    __shared__ unsigned short kt[2 * 64 * 64];   // [s][h] swizzled, dbuf
    __shared__ unsigned short vt[2 * 64 * 64];   // [h][s] swizzled, dbuf
    __shared__ float ptf[4 * 16 * 68];           // per-wave P [row][s], pad 4
    char* ktb = (char*)kt;
    char* vtb = (char*)vt;

    int tid  = threadIdx.x;
    int wave = tid >> 6, lane = tid & 63, quad = lane >> 4, l15 = lane & 15;
    int it = blockIdx.x >> 2, qq = blockIdx.x & 3;
    int b  = blockIdx.y;
    if (qq > it) return;
    int t0 = it * 64;
    size_t brow = (size_t)b * NT;

    bf16x8 qf[2];
    {
        const unsigned short* qp = qg + (brow + t0 + wave * 16 + l15) * NH + quad * 8;
        qf[0] = *(const bf16x8*)qp;
        qf[1] = *(const bf16x8*)(qp + 32);
    }
    int trow[4];
    float rinv[4];
#pragma unroll
    for (int r = 0; r < 4; ++r) {
        trow[r] = t0 + wave * 16 + quad * 4 + r;
        rinv[r] = 1.0f / l[brow + trow[r]];
    }

    f32x4 oacc[4];
#pragma unroll
    for (int nt = 0; nt < 4; ++nt) oacc[nt] = (f32x4){0.f, 0.f, 0.f, 0.f};

    // prologue: stage st=qq K,V into buf0
#pragma unroll
    for (int i = 0; i < 2; ++i) {
        int s = i * 256 + tid;
        int r = s >> 3, p = s & 7;
        int j = p ^ (r & 7);
        async_ld16(kg + (brow + qq * 64 + r) * NH + j * 8,
                   ktb + i * 4096 + wave * 1024);
        async_ld16(vtg + ((size_t)b * 64 + r) * NT + qq * 64 + j * 8,
                   vtb + i * 4096 + wave * 1024);
    }

    int cur = 0;
    for (int st = qq; st <= it; st += 4) {
        VM_DRAIN();                            // prev prefetch landed in LDS
        __syncthreads();                       // buf[cur] ready for all waves
        if (st + 4 <= it) {                    // prefetch next K,V tiles
#pragma unroll
            for (int i = 0; i < 2; ++i) {
                int s = i * 256 + tid;
                int r = s >> 3, p = s & 7;
                int j = p ^ (r & 7);
                async_ld16(kg + (brow + (st + 4) * 64 + r) * NH + j * 8,
                           ktb + (cur ^ 1) * 8192 + i * 4096 + wave * 1024);
                async_ld16(vtg + ((size_t)b * 64 + r) * NT + (st + 4) * 64 + j * 8,
                           vtb + (cur ^ 1) * 8192 + i * 4096 + wave * 1024);
            }
        }
        char* kb = ktb + cur * 8192;
        char* vb = vtb + cur * 8192;

        f32x4 sacc[4];
#pragma unroll
        for (int nt = 0; nt < 4; ++nt) sacc[nt] = (f32x4){0.f, 0.f, 0.f, 0.f};
#pragma unroll
        for (int c = 0; c < 2; ++c)
#pragma unroll
            for (int nt = 0; nt < 4; ++nt) {
                int n = nt * 16 + l15;
                int p = (c * 4 + quad) ^ (n & 7);
                bf16x8 kf = *(const bf16x8*)(kb + n * 128 + p * 16);
                sacc[nt] = __builtin_amdgcn_mfma_f32_16x16x32_bf16(qf[c], kf, sacc[nt], 0, 0, 0);
            }

        bool dia = (st == it);
#pragma unroll
        for (int nt = 0; nt < 4; ++nt) {
            int s_g = st * 64 + nt * 16 + l15;
#pragma unroll
            for (int r = 0; r < 4; ++r) {
                float p = __expf(sacc[nt][r]) * rinv[r];
                if (dia && s_g > trow[r]) p = 0.f;
                ptf[wave * 1088 + (quad * 4 + r) * 68 + nt * 16 + l15] = p;
            }
        }
        asm volatile("s_waitcnt lgkmcnt(0)" ::: "memory");  // wave-internal RAW

        // coalesced attn stores: 16 lanes x 16 B = 256 B per row
#pragma unroll
        for (int r = 0; r < 4; ++r) {
            int row = quad * 4 + r;
            float4 pv = *(const float4*)&ptf[wave * 1088 + row * 68 + l15 * 4];
            *(float4*)&attn[(brow + t0 + wave * 16 + row) * NT + st * 64 + l15 * 4] = pv;
        }

        // PV: A-frag from ptf (row l15, k = c*32+quad*8), B from vt
#pragma unroll
        for (int c = 0; c < 2; ++c) {
            const float* pp = &ptf[wave * 1088 + l15 * 68 + c * 32 + quad * 8];
            float4 a0 = *(const float4*)pp;
            float4 a1 = *(const float4*)(pp + 4);
            bf16x8 pf = cvt8(a0, a1);
#pragma unroll
            for (int nt = 0; nt < 4; ++nt) {
                int n = nt * 16 + l15;
                int p = (c * 4 + quad) ^ (n & 7);
                bf16x8 vf = *(const bf16x8*)(vb + n * 128 + p * 16);
                oacc[nt] = __builtin_amdgcn_mfma_f32_16x16x32_bf16(pf, vf, oacc[nt], 0, 0, 0);
            }
        }
        cur ^= 1;
    }

#pragma unroll
    for (int nt = 0; nt < 4; ++nt)
#pragma unroll
        for (int r = 0; r < 4; ++r)
            unsafeAtomicAdd(&res[(brow + trow[r]) * NH + nt * 16 + l15], oacc[nt][r]);
}

// ---------------------------------------------------------------------------
// Kernel 4: zero upper-triangle attn tiles. Grid (496, 8).
// ---------------------------------------------------------------------------
__global__ __launch_bounds__(256) void zero_kernel(float* __restrict__ attn) {
    int lt = blockIdx.x, b = blockIdx.y;
    float fr = sqrtf(8.f * (float)lt + 1.f);
    int i = (int)((fr + 1.f) * 0.5f);
    while (i * (i - 1) / 2 > lt) --i;
    while ((i + 1) * i / 2 <= lt) ++i;
    int j = lt - i * (i - 1) / 2;
    int it = j, st = i;
    size_t brow = (size_t)b * NT;
    int t0 = it * 64;
    float4 z4 = {0.f, 0.f, 0.f, 0.f};
    int tid = threadIdx.x;
    for (int k = 0; k < 4; ++k) {
        int f = tid + k * 256;
        int r = f >> 4, c4 = (f & 15) * 4;
        *(float4*)&attn[(brow + t0 + r) * NT + st * 64 + c4] = z4;
    }
}

// ---------------------------------------------------------------------------
extern "C" void kernel_launch(void* const* d_in, const int* in_sizes, int n_in,
                              void* d_out, int out_size, void* d_ws, size_t ws_size,
                              hipStream_t stream) {
    const float* x  = (const float*)d_in[0];
    const float* Wq = (const float*)d_in[1];
    const float* Wk = (const float*)d_in[2];
    const float* Wv = (const float*)d_in[3];

    unsigned short* ws  = (unsigned short*)d_ws;
    unsigned short* Wt  = ws;                          // 3*64*1024 bf16
    unsigned short* qkv = ws + 3 * 64 * 1024;          // 2*16384*64 bf16 (q,k)
    unsigned short* v_t = qkv + 2 * 16384 * 64;        // 16384*64 bf16 [b][h][t]
    float* l = (float*)(v_t + 16384 * 64);             // 16384 fp32

    float* res  = (float*)d_out;                       // [8,2048,64]
    float* attn = res + (size_t)NB * NT * NH;          // [8,2048,2048]

    hipMemsetAsync(l, 0, (size_t)NB * NT * sizeof(float), stream);
    hipMemsetAsync(res, 0, (size_t)NB * NT * NH * sizeof(float), stream);

    hipLaunchKernelGGL(wt_kernel, dim3(48), dim3(256), 0, stream, Wq, Wk, Wv, Wt);
    hipLaunchKernelGGL(qkv_kernel, dim3(512), dim3(256), 0, stream, x, Wt, qkv, v_t);

    const unsigned short* qg = qkv;
    const unsigned short* kg = qkv + 16384 * 64;

    hipLaunchKernelGGL(lsum_kernel, dim3(128, 8), dim3(256), 0, stream, qg, kg, l);
    hipLaunchKernelGGL(attn_m_kernel, dim3(128, 8), dim3(256), 0, stream,
                       qg, kg, v_t, l, res, attn);
    hipLaunchKernelGGL(zero_kernel, dim3(496, 8), dim3(256), 0, stream, attn);
}

// Round 6
// 227.187 us; speedup vs baseline: 1.2402x; 1.0130x over previous
//
#include <hip/hip_runtime.h>
#include <hip/hip_bf16.h>

// Inputs fp32, outputs fp32. Internal bf16 MFMA pipeline.
// R12: attn-side parallelism + dispatch-count attack (qkv untouched for
// attribution). (1) qq-split 4->8 in lsum/attn_m: max tile-iters per block
// 8->4, ~2x blocks -> more co-resident blocks to hide stage latency, and
// the critical-path block halves. (2) zero_kernel folded into attn_m: each
// lower tile-visit (it,st), st<it, also zeroes the mirrored upper tile
// (st,it) -- bijective coverage, one less dispatch, zero-stores overlap
// compute. R11 lesson: intra-kernel T3 pipelining was neutral; R7 lesson:
// keep coalesced global_load_lds staging.

typedef __attribute__((ext_vector_type(8))) short bf16x8;
typedef __attribute__((ext_vector_type(4))) float f32x4;

#define NB 8
#define NT 2048
#define NC 1024
#define NH 64

#define VM_DRAIN() asm volatile("s_waitcnt vmcnt(0)" ::: "memory")

__device__ __forceinline__ unsigned short f2bf(float f) {
    unsigned int u = __builtin_bit_cast(unsigned int, f);
    u += 0x7fffu + ((u >> 16) & 1u);   // RNE
    return (unsigned short)(u >> 16);
}

__device__ __forceinline__ bf16x8 cvt8(float4 a, float4 b) {
    union { bf16x8 v; __hip_bfloat162 h[4]; } u;
    u.h[0] = __float22bfloat162_rn(make_float2(a.x, a.y));
    u.h[1] = __float22bfloat162_rn(make_float2(a.z, a.w));
    u.h[2] = __float22bfloat162_rn(make_float2(b.x, b.y));
    u.h[3] = __float22bfloat162_rn(make_float2(b.z, b.w));
    return u.v;
}

// async 16B global->LDS; lds ptr must be wave-uniform (HW adds lane*16).
__device__ __forceinline__ void async_ld16(const void* g, const void* l) {
    __builtin_amdgcn_global_load_lds(
        (const __attribute__((address_space(1))) unsigned int*)g,
        (__attribute__((address_space(3))) unsigned int*)(unsigned int)(unsigned long long)l,
        16, 0, 0);
}

// ---------------------------------------------------------------------------
// Kernel 0: W fp32 [1024][64] -> Wt bf16 [3][64][1024] (transposed), 1/32
// score scale folded into Wq (power of two, lossless).
// ---------------------------------------------------------------------------
__global__ __launch_bounds__(256) void wt_kernel(
        const float* __restrict__ Wq,
        const float* __restrict__ Wk,
        const float* __restrict__ Wv,
        unsigned short* __restrict__ Wt) {
    __shared__ float tile[64][65];
    int m  = blockIdx.x >> 4;
    int k0 = (blockIdx.x & 15) * 64;
    const float* W = (m == 0) ? Wq : ((m == 1) ? Wk : Wv);
    int tid = threadIdx.x;
    for (int i = 0; i < 4; ++i) {
        int f = tid + i * 256;
        int r = f >> 4, c4 = (f & 15) * 4;
        float4 v = *(const float4*)&W[(size_t)(k0 + r) * 64 + c4];
        tile[r][c4 + 0] = v.x; tile[r][c4 + 1] = v.y;
        tile[r][c4 + 2] = v.z; tile[r][c4 + 3] = v.w;
    }
    __syncthreads();
    int n  = tid & 63;
    int kq = (tid >> 6) * 16;
    float scale = (m == 0) ? 0.03125f : 1.0f;
    __attribute__((aligned(16))) unsigned short outv[16];
    for (int j = 0; j < 16; ++j)
        outv[j] = f2bf(tile[kq + j][n] * scale);
    unsigned short* dst = &Wt[(size_t)m * (64 * 1024) + (size_t)n * 1024 + k0 + kq];
    *(uint4*)dst       = *(const uint4*)&outv[0];
    *(uint4*)(dst + 8) = *(const uint4*)&outv[8];
}

// ---------------------------------------------------------------------------
// Kernel 1: qkv GEMM. Grid 512: 32 rows/block, N=192 (q|k|v). Unchanged from
// R11: A + B double-buffered via global_load_lds (XOR swizzle); one barrier
// per K-step, prefetch pre-compute, explicit vmcnt(0) drain. 64 KB LDS.
// ---------------------------------------------------------------------------
__global__ __launch_bounds__(256) void qkv_kernel(
        const float* __restrict__ x,
        const unsigned short* __restrict__ Wt,
        unsigned short* __restrict__ qkv,
        unsigned short* __restrict__ v_t) {
    __shared__ char smem[65536];

    int tid  = threadIdx.x;
    int wave = tid >> 6, lane = tid & 63, quad = lane >> 4, l15 = lane & 15;
    int row0 = blockIdx.x * 32;

    f32x4 acc[2][3];
#pragma unroll
    for (int rt = 0; rt < 2; ++rt)
#pragma unroll
        for (int j = 0; j < 3; ++j) acc[rt][j] = (f32x4){0.f, 0.f, 0.f, 0.f};

    // prologue: stage kb=0 into buf0
#pragma unroll
    for (int i = 0; i < 2; ++i) {              // A: 32 rows x 256 B
        int s = i * 256 + tid;
        int m = s >> 4, p = s & 15;
        int j = (p & 8) | ((p & 7) ^ (m & 7));
        async_ld16(x + (size_t)(row0 + m) * NC + j * 4,
                   smem + i * 4096 + wave * 1024);
    }
#pragma unroll
    for (int i = 0; i < 6; ++i) {              // B: 192 rows x 128 B
        int s = i * 256 + tid;
        int n = s >> 3, p = s & 7;
        int j = p ^ (n & 7);
        async_ld16(Wt + (size_t)n * NC + j * 8,
                   smem + 8192 + i * 4096 + wave * 1024);
    }

    int cur = 0;
    for (int kb = 0; kb < 16; ++kb) {
        VM_DRAIN();                            // prev prefetch landed in LDS
        __syncthreads();                       // buf[cur] ready for all waves
        if (kb < 15) {                         // prefetch kb+1 -> buf[cur^1]
            char* nb = smem + (cur ^ 1) * 32768;
#pragma unroll
            for (int i = 0; i < 2; ++i) {
                int s = i * 256 + tid;
                int m = s >> 4, p = s & 15;
                int j = (p & 8) | ((p & 7) ^ (m & 7));
                async_ld16(x + (size_t)(row0 + m) * NC + (kb + 1) * 64 + j * 4,
                           nb + i * 4096 + wave * 1024);
            }
#pragma unroll
            for (int i = 0; i < 6; ++i) {
                int s = i * 256 + tid;
                int n = s >> 3, p = s & 7;
                int j = p ^ (n & 7);
                async_ld16(Wt + (size_t)n * NC + (kb + 1) * 64 + j * 8,
                           nb + 8192 + i * 4096 + wave * 1024);
            }
        }
        char* Ab = smem + cur * 32768;
        char* Bb = Ab + 8192;
#pragma unroll
        for (int c = 0; c < 2; ++c) {
            bf16x8 af[2];
#pragma unroll
            for (int rt = 0; rt < 2; ++rt) {
                int m  = rt * 16 + l15;
                int j0 = c * 8 + quad * 2;
                int p0 = (j0 & 8) | ((j0 & 7) ^ (m & 7));
                int p1 = (j0 & 8) | (((j0 + 1) & 7) ^ (m & 7));
                float4 a0 = *(const float4*)(Ab + m * 256 + p0 * 16);
                float4 a1 = *(const float4*)(Ab + m * 256 + p1 * 16);
                af[rt] = cvt8(a0, a1);
            }
#pragma unroll
            for (int jj = 0; jj < 3; ++jj) {
                int n = (wave * 3 + jj) * 16 + l15;
                int p = (c * 4 + quad) ^ (n & 7);
                bf16x8 bf = *(const bf16x8*)(Bb + n * 128 + p * 16);
#pragma unroll
                for (int rt = 0; rt < 2; ++rt)
                    acc[rt][jj] = __builtin_amdgcn_mfma_f32_16x16x32_bf16(
                        af[rt], bf, acc[rt][jj], 0, 0, 0);
            }
        }
        cur ^= 1;
    }

    int b = row0 >> 11;
#pragma unroll
    for (int jj = 0; jj < 3; ++jj) {
        int g   = wave * 3 + jj;
        int mat = g >> 2;
        int col = (g & 3) * 16 + l15;
#pragma unroll
        for (int rt = 0; rt < 2; ++rt) {
            int rowb = row0 + rt * 16 + quad * 4;
            if (mat < 2) {
#pragma unroll
                for (int r = 0; r < 4; ++r)
                    qkv[(size_t)mat * (16384 * 64) + (size_t)(rowb + r) * 64 + col] =
                        f2bf(acc[rt][jj][r]);
            } else {
                union { unsigned long long q; unsigned short us[4]; } pk;
#pragma unroll
                for (int r = 0; r < 4; ++r) pk.us[r] = f2bf(acc[rt][jj][r]);
                *(unsigned long long*)&v_t[((size_t)b * 64 + col) * NT + (rowb & 2047)] = pk.q;
            }
        }
    }
}

// ---------------------------------------------------------------------------
// Kernel 2: rowsums. Grid (256, 8): bx = it*8 + qq; tiles st = qq, qq+8, ...
// (max 4 tile-iters/block). K tile double-buffered, one barrier per tile.
// ---------------------------------------------------------------------------
__global__ __launch_bounds__(256) void lsum_kernel(
        const unsigned short* __restrict__ qg,
        const unsigned short* __restrict__ kg,
        float* __restrict__ l) {
    __shared__ unsigned short kt[2 * 64 * 64];
    char* ktb = (char*)kt;
    int tid  = threadIdx.x;
    int wave = tid >> 6, lane = tid & 63, quad = lane >> 4, l15 = lane & 15;
    int it = blockIdx.x >> 3, qq = blockIdx.x & 7;
    int b  = blockIdx.y;
    if (qq > it) return;
    int t0 = it * 64;
    size_t brow = (size_t)b * NT;

    bf16x8 qf[2];
    {
        const unsigned short* qp = qg + (brow + t0 + wave * 16 + l15) * NH + quad * 8;
        qf[0] = *(const bf16x8*)qp;
        qf[1] = *(const bf16x8*)(qp + 32);
    }
    int trow[4];
#pragma unroll
    for (int r = 0; r < 4; ++r) trow[r] = t0 + wave * 16 + quad * 4 + r;

    // prologue: stage st=qq into buf0
#pragma unroll
    for (int i = 0; i < 2; ++i) {
        int s = i * 256 + tid;
        int r = s >> 3, p = s & 7;
        int j = p ^ (r & 7);
        async_ld16(kg + (brow + qq * 64 + r) * NH + j * 8,
                   ktb + i * 4096 + wave * 1024);
    }

    float rs[4] = {0.f, 0.f, 0.f, 0.f};
    int cur = 0;

    for (int st = qq; st <= it; st += 8) {
        VM_DRAIN();                            // prev prefetch landed in LDS
        __syncthreads();                       // buf[cur] ready for all waves
        if (st + 8 <= it) {                    // prefetch next K tile
#pragma unroll
            for (int i = 0; i < 2; ++i) {
                int s = i * 256 + tid;
                int r = s >> 3, p = s & 7;
                int j = p ^ (r & 7);
                async_ld16(kg + (brow + (st + 8) * 64 + r) * NH + j * 8,
                           ktb + (cur ^ 1) * 8192 + i * 4096 + wave * 1024);
            }
        }
        char* kb = ktb + cur * 8192;

        f32x4 sacc[4];
#pragma unroll
        for (int nt = 0; nt < 4; ++nt) sacc[nt] = (f32x4){0.f, 0.f, 0.f, 0.f};
#pragma unroll
        for (int c = 0; c < 2; ++c)
#pragma unroll
            for (int nt = 0; nt < 4; ++nt) {
                int n = nt * 16 + l15;
                int p = (c * 4 + quad) ^ (n & 7);
                bf16x8 kf = *(const bf16x8*)(kb + n * 128 + p * 16);
                sacc[nt] = __builtin_amdgcn_mfma_f32_16x16x32_bf16(qf[c], kf, sacc[nt], 0, 0, 0);
            }
        bool dia = (st == it);
#pragma unroll
        for (int nt = 0; nt < 4; ++nt) {
            int s_g = st * 64 + nt * 16 + l15;
#pragma unroll
            for (int r = 0; r < 4; ++r) {
                float e = __expf(sacc[nt][r]);
                if (dia && s_g > trow[r]) e = 0.f;
                rs[r] += e;
            }
        }
        cur ^= 1;
    }
#pragma unroll
    for (int r = 0; r < 4; ++r) {
        float v = rs[r];
        v += __shfl_xor(v, 1, 16);
        v += __shfl_xor(v, 2, 16);
        v += __shfl_xor(v, 4, 16);
        v += __shfl_xor(v, 8, 16);
        if (l15 == 0)
            unsafeAtomicAdd(&l[brow + trow[r]], v);
    }
}

// ---------------------------------------------------------------------------
// Kernel 3: attn write + PV + upper-tri zero. Grid (256, 8): bx = it*8 + qq,
// tiles strided 8 (max 4 iters/block). Each visit of lower tile (it,st) with
// st<it also zeroes the mirrored upper tile (st,it) -- bijective coverage,
// replaces zero_kernel. K/V^T double-buffered, one barrier per tile.
// ---------------------------------------------------------------------------
__global__ __launch_bounds__(256) void attn_m_kernel(
        const unsigned short* __restrict__ qg,
        const unsigned short* __restrict__ kg,
        const unsigned short* __restrict__ vtg,
        const float* __restrict__ l,
        float* __restrict__ res,
        float* __restrict__ attn) {
    __shared__ unsigned short kt[2 * 64 * 64];   // [s][h] swizzled, dbuf
    __shared__ unsigned short vt[2 * 64 * 64];   // [h][s] swizzled, dbuf
    __shared__ float ptf[4 * 16 * 68];           // per-wave P [row][s], pad 4
    char* ktb = (char*)kt;
    char* vtb = (char*)vt;

    int tid  = threadIdx.x;
    int wave = tid >> 6, lane = tid & 63, quad = lane >> 4, l15 = lane & 15;
    int it = blockIdx.x >> 3, qq = blockIdx.x & 7;
    int b  = blockIdx.y;
    if (qq > it) return;
    int t0 = it * 64;
    size_t brow = (size_t)b * NT;

    bf16x8 qf[2];
    {
        const unsigned short* qp = qg + (brow + t0 + wave * 16 + l15) * NH + quad * 8;
        qf[0] = *(const bf16x8*)qp;
        qf[1] = *(const bf16x8*)(qp + 32);
    }
    int trow[4];
    float rinv[4];
#pragma unroll
    for (int r = 0; r < 4; ++r) {
        trow[r] = t0 + wave * 16 + quad * 4 + r;
        rinv[r] = 1.0f / l[brow + trow[r]];
    }

    f32x4 oacc[4];
#pragma unroll
    for (int nt = 0; nt < 4; ++nt) oacc[nt] = (f32x4){0.f, 0.f, 0.f, 0.f};

    // prologue: stage st=qq K,V into buf0
#pragma unroll
    for (int i = 0; i < 2; ++i) {
        int s = i * 256 + tid;
        int r = s >> 3, p = s & 7;
        int j = p ^ (r & 7);
        async_ld16(kg + (brow + qq * 64 + r) * NH + j * 8,
                   ktb + i * 4096 + wave * 1024);
        async_ld16(vtg + ((size_t)b * 64 + r) * NT + qq * 64 + j * 8,
                   vtb + i * 4096 + wave * 1024);
    }

    int cur = 0;
    for (int st = qq; st <= it; st += 8) {
        VM_DRAIN();                            // prev prefetch landed in LDS
        __syncthreads();                       // buf[cur] ready for all waves
        if (st + 8 <= it) {                    // prefetch next K,V tiles
#pragma unroll
            for (int i = 0; i < 2; ++i) {
                int s = i * 256 + tid;
                int r = s >> 3, p = s & 7;
                int j = p ^ (r & 7);
                async_ld16(kg + (brow + (st + 8) * 64 + r) * NH + j * 8,
                           ktb + (cur ^ 1) * 8192 + i * 4096 + wave * 1024);
                async_ld16(vtg + ((size_t)b * 64 + r) * NT + (st + 8) * 64 + j * 8,
                           vtb + (cur ^ 1) * 8192 + i * 4096 + wave * 1024);
            }
        }
        char* kb = ktb + cur * 8192;
        char* vb = vtb + cur * 8192;

        f32x4 sacc[4];
#pragma unroll
        for (int nt = 0; nt < 4; ++nt) sacc[nt] = (f32x4){0.f, 0.f, 0.f, 0.f};
#pragma unroll
        for (int c = 0; c < 2; ++c)
#pragma unroll
            for (int nt = 0; nt < 4; ++nt) {
                int n = nt * 16 + l15;
                int p = (c * 4 + quad) ^ (n & 7);
                bf16x8 kf = *(const bf16x8*)(kb + n * 128 + p * 16);
                sacc[nt] = __builtin_amdgcn_mfma_f32_16x16x32_bf16(qf[c], kf, sacc[nt], 0, 0, 0);
            }

        bool dia = (st == it);
#pragma unroll
        for (int nt = 0; nt < 4; ++nt) {
            int s_g = st * 64 + nt * 16 + l15;
#pragma unroll
            for (int r = 0; r < 4; ++r) {
                float p = __expf(sacc[nt][r]) * rinv[r];
                if (dia && s_g > trow[r]) p = 0.f;
                ptf[wave * 1088 + (quad * 4 + r) * 68 + nt * 16 + l15] = p;
            }
        }
        asm volatile("s_waitcnt lgkmcnt(0)" ::: "memory");  // wave-internal RAW

        // coalesced attn stores: 16 lanes x 16 B = 256 B per row
#pragma unroll
        for (int r = 0; r < 4; ++r) {
            int row = quad * 4 + r;
            float4 pv = *(const float4*)&ptf[wave * 1088 + row * 68 + l15 * 4];
            *(float4*)&attn[(brow + t0 + wave * 16 + row) * NT + st * 64 + l15 * 4] = pv;
        }

        // zero the mirrored upper-tri tile (st,it) -- bijective with the
        // lower-tri visit; replaces zero_kernel. Diagonal has no partner.
        if (st < it) {
            float4 z4 = {0.f, 0.f, 0.f, 0.f};
#pragma unroll
            for (int k = 0; k < 4; ++k) {
                int f = tid + k * 256;
                int r = f >> 4, c4 = (f & 15) * 4;
                *(float4*)&attn[(brow + st * 64 + r) * NT + t0 + c4] = z4;
            }
        }

        // PV: A-frag from ptf (row l15, k = c*32+quad*8), B from vt
#pragma unroll
        for (int c = 0; c < 2; ++c) {
            const float* pp = &ptf[wave * 1088 + l15 * 68 + c * 32 + quad * 8];
            float4 a0 = *(const float4*)pp;
            float4 a1 = *(const float4*)(pp + 4);
            bf16x8 pf = cvt8(a0, a1);
#pragma unroll
            for (int nt = 0; nt < 4; ++nt) {
                int n = nt * 16 + l15;
                int p = (c * 4 + quad) ^ (n & 7);
                bf16x8 vf = *(const bf16x8*)(vb + n * 128 + p * 16);
                oacc[nt] = __builtin_amdgcn_mfma_f32_16x16x32_bf16(pf, vf, oacc[nt], 0, 0, 0);
            }
        }
        cur ^= 1;
    }

#pragma unroll
    for (int nt = 0; nt < 4; ++nt)
#pragma unroll
        for (int r = 0; r < 4; ++r)
            unsafeAtomicAdd(&res[(brow + trow[r]) * NH + nt * 16 + l15], oacc[nt][r]);
}

// ---------------------------------------------------------------------------
extern "C" void kernel_launch(void* const* d_in, const int* in_sizes, int n_in,
                              void* d_out, int out_size, void* d_ws, size_t ws_size,
                              hipStream_t stream) {
    const float* x  = (const float*)d_in[0];
    const float* Wq = (const float*)d_in[1];
    const float* Wk = (const float*)d_in[2];
    const float* Wv = (const float*)d_in[3];

    unsigned short* ws  = (unsigned short*)d_ws;
    unsigned short* Wt  = ws;                          // 3*64*1024 bf16
    unsigned short* qkv = ws + 3 * 64 * 1024;          // 2*16384*64 bf16 (q,k)
    unsigned short* v_t = qkv + 2 * 16384 * 64;        // 16384*64 bf16 [b][h][t]
    float* l = (float*)(v_t + 16384 * 64);             // 16384 fp32

    float* res  = (float*)d_out;                       // [8,2048,64]
    float* attn = res + (size_t)NB * NT * NH;          // [8,2048,2048]

    hipMemsetAsync(l, 0, (size_t)NB * NT * sizeof(float), stream);
    hipMemsetAsync(res, 0, (size_t)NB * NT * NH * sizeof(float), stream);

    hipLaunchKernelGGL(wt_kernel, dim3(48), dim3(256), 0, stream, Wq, Wk, Wv, Wt);
    hipLaunchKernelGGL(qkv_kernel, dim3(512), dim3(256), 0, stream, x, Wt, qkv, v_t);

    const unsigned short* qg = qkv;
    const unsigned short* kg = qkv + 16384 * 64;

    hipLaunchKernelGGL(lsum_kernel, dim3(256, 8), dim3(256), 0, stream, qg, kg, l);
    hipLaunchKernelGGL(attn_m_kernel, dim3(256, 8), dim3(256), 0, stream,
                       qg, kg, v_t, l, res, attn);
}